// Round 2
// baseline (4749.779 us; speedup 1.0000x reference)
//
#include <hip/hip_runtime.h>
#include <cstdint>

// SplineConv MeshEncoder: 3 layers, K=3 DIM=3 M=27, dims 3->64->64->64.
// R1: MFMA Phase B + LDS-atomic Phase A.
//  - 1/deg folded into precomputed edge weights; root term appended as 64
//    extra K slots -> layer = pure GEMM acc(n,1792) @ [W;Wr] + b, ReLU.
//  - 64-ch layers: 8 nodes/block, 4 waves. Phase A: ds_add_f32 atomics into
//    LDS acc (stride 1796 pad -> <=2-way bank alias, free). Phase B:
//    mfma_f32_16x16x32_bf16 over 56 K-chunks, B-frags from pre-swizzled bf16
//    Wb (coalesced 16B/lane, L2-resident).

constexpr int MM = 27;

typedef __attribute__((ext_vector_type(8))) short short8;
typedef __attribute__((ext_vector_type(4))) float floatx4;

__device__ inline short f2bf(float f) {
    union { float f; unsigned u; } x; x.f = f;
    unsigned r = x.u + 0x7FFF + ((x.u >> 16) & 1);   // round-to-nearest-even
    return (short)(r >> 16);
}

// ---------------- preprocessing ----------------

__global__ void count_kernel(const int* __restrict__ ei, int* __restrict__ count, int E) {
    int e = blockIdx.x * blockDim.x + threadIdx.x;
    if (e < E) atomicAdd(&count[ei[E + e]], 1);
}

// Single-block scan: shfl-based, 3 barriers per 1024-tile.
__global__ __launch_bounds__(1024) void scan_kernel(const int* __restrict__ count,
                                                    int* __restrict__ row_ptr,
                                                    int* __restrict__ cursor, int N) {
    __shared__ int wsum[16];
    __shared__ int carry_s;
    int tid = threadIdx.x, lane = tid & 63, wid = tid >> 6;
    if (tid == 0) carry_s = 0;
    __syncthreads();
    for (int base = 0; base < N; base += 1024) {
        int i = base + tid;
        int v = (i < N) ? count[i] : 0;
        int incl = v;
#pragma unroll
        for (int off = 1; off < 64; off <<= 1) {
            int t = __shfl_up(incl, off, 64);
            if (lane >= off) incl += t;
        }
        if (lane == 63) wsum[wid] = incl;
        __syncthreads();
        if (tid < 16) {
            int w = wsum[tid];
#pragma unroll
            for (int off = 1; off < 16; off <<= 1) {
                int t = __shfl_up(w, off, 16);
                if ((tid & 15) >= off) w += t;
            }
            wsum[tid] = w;   // inclusive wave sums
        }
        __syncthreads();
        int waveoff = (wid > 0) ? wsum[wid - 1] : 0;
        int carry = carry_s;
        int excl = carry + waveoff + incl - v;
        if (i < N) { row_ptr[i] = excl; cursor[i] = excl; }
        __syncthreads();
        if (tid == 1023) carry_s = carry + waveoff + incl;
        __syncthreads();
    }
    if (threadIdx.x == 0) row_ptr[N] = carry_s;
}

// Per edge: 8 corner weights (pre-scaled by 1/deg) + packed kernel indices,
// scattered to dst-sorted position. meta = src | (dst&255)<<20.
__global__ void basis_sort_kernel(const int* __restrict__ ei, const float* __restrict__ attr,
                                  const int* __restrict__ count, int* __restrict__ cursor,
                                  int* __restrict__ s_meta,
                                  unsigned long long* __restrict__ s_kidx,
                                  float* __restrict__ s_w, int E) {
    int e = blockIdx.x * blockDim.x + threadIdx.x;
    if (e >= E) return;
    int src = ei[e];
    int dst = ei[E + e];
    float f[3]; int i0[3];
#pragma unroll
    for (int d = 0; d < 3; d++) {
        float pos = attr[e * 3 + d] * 2.0f;          // K-1 = 2
        float fl = floorf(pos);
        fl = fminf(fmaxf(fl, 0.0f), 1.0f);           // clip to [0, K-2]
        i0[d] = (int)fl;
        f[d] = pos - fl;
    }
    float invd = 1.0f / fmaxf((float)count[dst], 1.0f);
    int p = atomicAdd(&cursor[dst], 1);
    s_meta[p] = src | ((dst & 255) << 20);
    unsigned long long packed = 0;
#pragma unroll
    for (int c = 0; c < 8; c++) {
        float w = 1.0f;
        int kidx = 0;
        const int strides[3] = {1, 3, 9};
#pragma unroll
        for (int d = 0; d < 3; d++) {
            int off = (c >> d) & 1;
            w *= off ? f[d] : (1.0f - f[d]);
            kidx += (i0[d] + off) * strides[d];
        }
        packed |= ((unsigned long long)(kidx & 0xFF)) << (8 * c);
        s_w[(size_t)p * 8 + c] = w * invd;
    }
    s_kidx[p] = packed;
}

// Pre-swizzle [W(1728,64); Wr(64,64)] into bf16 MFMA B-fragment order:
// wb[((t*56+c)*64+l)*8 + j] = bf16( Wcat[c*32+(l>>4)*8+j][t*16+(l&15)] )
__global__ void build_wb(const float* __restrict__ W, const float* __restrict__ Wr,
                         unsigned short* __restrict__ wb) {
    int idx = blockIdx.x * blockDim.x + threadIdx.x;   // [0, 4*56*64)
    if (idx >= 4 * 56 * 64) return;
    int l = idx & 63;
    int c = (idx >> 6) % 56;
    int t = idx / (56 * 64);
    int q = l >> 4, o = t * 16 + (l & 15);
    short8 out;
#pragma unroll
    for (int j = 0; j < 8; j++) {
        int k = c * 32 + q * 8 + j;
        float v = (k < 1728) ? W[(size_t)k * 64 + o] : Wr[(size_t)(k - 1728) * 64 + o];
        out[j] = f2bf(v);
    }
    *(short8*)(wb + (size_t)idx * 8) = out;
}

// ---------------- layer 0 (CIN=3) ----------------
__global__ __launch_bounds__(256) void layer0_kernel(
    const float* __restrict__ x, const float* __restrict__ W0,
    const float* __restrict__ Wr, const float* __restrict__ bias,
    const int* __restrict__ row_ptr, const int* __restrict__ s_meta,
    const unsigned long long* __restrict__ s_kidx, const float* __restrict__ s_w,
    float* __restrict__ h_out, int N) {
    constexpr int NPB = 32, KT = 84;                  // 27*3 spline + 3 root
    __shared__ __align__(16) float acc[NPB * KT];     // 10.75 KB
    int tid = threadIdx.x, lane = tid & 63, wv = tid >> 6;
    int n0 = blockIdx.x * NPB;
    for (int k = tid; k < NPB * KT; k += 256) acc[k] = 0.0f;
    __syncthreads();
    for (int idx = tid; idx < NPB * 3; idx += 256) {  // root slots
        int g = idx / 3, i = idx - g * 3;
        int n = n0 + g;
        if (n < N) acc[g * KT + 81 + i] = x[(size_t)n * 3 + i];
    }
    int rs = row_ptr[n0];
    int nend = min(n0 + NPB, N);
    int re = row_ptr[nend];
    int c = lane / 3, i = lane - c * 3;
    bool act = (lane < 24);
    for (int e = rs + wv; e < re; e += 4) {
        int meta = s_meta[e];
        int src = meta & 0xFFFFF;
        int g = (meta >> 20) & 31;
        if (act) {
            unsigned long long kp = s_kidx[e];
            float w = s_w[(size_t)e * 8 + c];
            float xj = x[(size_t)src * 3 + i];
            int kidx = (int)((kp >> (8 * c)) & 0xFF);
            __hip_atomic_fetch_add(&acc[g * KT + kidx * 3 + i], w * xj,
                                   __ATOMIC_RELAXED, __HIP_MEMORY_SCOPE_WORKGROUP);
        }
    }
    __syncthreads();
    // Phase B: o = lane, W held in 84 registers, 8 node-groups per wave.
    int o = lane;
    float wreg[KT];
#pragma unroll
    for (int k = 0; k < KT; k++)
        wreg[k] = (k < 81) ? W0[k * 64 + o] : Wr[(k - 81) * 64 + o];
    float bv = bias[o];
    for (int g = wv; g < NPB; g += 4) {
        int n = n0 + g;
        if (n >= N) break;
        float s = bv;
#pragma unroll
        for (int k4 = 0; k4 < KT; k4 += 4) {
            floatx4 a = *(const floatx4*)&acc[g * KT + k4];
            s += a.x * wreg[k4] + a.y * wreg[k4 + 1] + a.z * wreg[k4 + 2] + a.w * wreg[k4 + 3];
        }
        h_out[(size_t)n * 64 + o] = fmaxf(s, 0.0f);
    }
}

// ---------------- 64-ch layers (MFMA) ----------------
__global__ __launch_bounds__(256) void layer64_kernel(
    const float* __restrict__ h_in, const unsigned short* __restrict__ wb,
    const float* __restrict__ bias, const int* __restrict__ row_ptr,
    const int* __restrict__ s_meta, const unsigned long long* __restrict__ s_kidx,
    const float* __restrict__ s_w, float* __restrict__ h_out, int N) {
    constexpr int NPB = 8;
    constexpr int KROW = 1792;           // 27*64 spline + 64 root
    constexpr int KPAD = 1796;           // stride pad: 1796%32=4 -> <=2-way bank alias
    __shared__ __align__(16) float acc[NPB * KPAD];   // 57,472 B -> 2 blocks/CU
    int tid = threadIdx.x, lane = tid & 63, wv = tid >> 6;
    int n0 = blockIdx.x * NPB;

    for (int k = tid; k < NPB * KPAD; k += 256) acc[k] = 0.0f;
    __syncthreads();

    for (int g = wv; g < NPB; g += 4) {   // root slots
        int n = n0 + g;
        if (n < N) acc[g * KPAD + 1728 + lane] = h_in[(size_t)n * 64 + lane];
    }

    // Phase A: 4 waves stride the block's CSR edge range; fire-and-forget
    // LDS atomics (lane = channel, stride-1 -> conflict-free).
    int rs = row_ptr[n0];
    int nend = min(n0 + NPB, N);
    int re = row_ptr[nend];
    for (int e = rs + wv; e < re; e += 4) {
        int meta = s_meta[e];
        int src = meta & 0xFFFFF;
        int g = (meta >> 20) & 7;
        unsigned long long kp = s_kidx[e];
        const floatx4* wp = (const floatx4*)(s_w + (size_t)e * 8);
        floatx4 w0 = wp[0], w1 = wp[1];
        float xj = h_in[(size_t)src * 64 + lane];
        float* arow = &acc[g * KPAD + lane];
        float wc[8] = {w0.x, w0.y, w0.z, w0.w, w1.x, w1.y, w1.z, w1.w};
#pragma unroll
        for (int c = 0; c < 8; c++) {
            int kidx = (int)((kp >> (8 * c)) & 0xFF);
            __hip_atomic_fetch_add(&arow[kidx * 64], wc[c] * xj,
                                   __ATOMIC_RELAXED, __HIP_MEMORY_SCOPE_WORKGROUP);
        }
    }
    __syncthreads();

    // Phase B: wave wv computes output tile t=wv (16 outs) for the 8 nodes.
    // A rows m>=8 duplicate rows 0..7 (discarded at store).
    int t = wv;
    int mq = lane >> 4;                  // k-quad
    const float* arow = &acc[(lane & 7) * KPAD];
    floatx4 facc = {0.0f, 0.0f, 0.0f, 0.0f};
    const unsigned short* wbp = wb + ((size_t)(t * 56) * 64 + lane) * 8;
#pragma unroll 2
    for (int c = 0; c < 56; c++) {
        int ka = c * 32 + mq * 8;
        floatx4 a0 = *(const floatx4*)(arow + ka);       // ds_read_b128
        floatx4 a1 = *(const floatx4*)(arow + ka + 4);
        short8 af;
        af[0] = f2bf(a0.x); af[1] = f2bf(a0.y); af[2] = f2bf(a0.z); af[3] = f2bf(a0.w);
        af[4] = f2bf(a1.x); af[5] = f2bf(a1.y); af[6] = f2bf(a1.z); af[7] = f2bf(a1.w);
        short8 bf = *(const short8*)(wbp + (size_t)c * 64 * 8);  // 16B coalesced
        facc = __builtin_amdgcn_mfma_f32_16x16x32_bf16(af, bf, facc, 0, 0, 0);
    }

    // Epilogue: C/D layout col=lane&15, row=(lane>>4)*4+r. rows(m)=nodes.
    int o = t * 16 + (lane & 15);
    float bv = bias[o];
#pragma unroll
    for (int r = 0; r < 4; r++) {
        int m = (lane >> 4) * 4 + r;
        if (m < 8) {
            int n = n0 + m;
            if (n < N) h_out[(size_t)n * 64 + o] = fmaxf(facc[r] + bv, 0.0f);
        }
    }
}

extern "C" void kernel_launch(void* const* d_in, const int* in_sizes, int n_in,
                              void* d_out, int out_size, void* d_ws, size_t ws_size,
                              hipStream_t stream) {
    (void)n_in; (void)out_size; (void)ws_size;
    const float* x    = (const float*)d_in[0];
    const int*   ei   = (const int*)d_in[1];
    const float* attr = (const float*)d_in[2];
    const float* W0 = (const float*)d_in[3];
    const float* R0 = (const float*)d_in[4];
    const float* B0 = (const float*)d_in[5];
    const float* W1 = (const float*)d_in[6];
    const float* R1 = (const float*)d_in[7];
    const float* B1 = (const float*)d_in[8];
    const float* W2 = (const float*)d_in[9];
    const float* R2 = (const float*)d_in[10];
    const float* B2 = (const float*)d_in[11];
    const int N = in_sizes[0] / 3;
    const int E = in_sizes[1] / 2;

    char* ws = (char*)d_ws;
    size_t off = 0;
    auto alloc = [&](size_t bytes) {
        size_t cur = off;
        off = (off + bytes + 255) & ~(size_t)255;
        return cur;
    };
    int* row_ptr = (int*)(ws + alloc((size_t)(N + 1) * 4));
    int* count   = (int*)(ws + alloc((size_t)N * 4));
    int* cursor  = (int*)(ws + alloc((size_t)N * 4));
    int* s_meta  = (int*)(ws + alloc((size_t)E * 4));
    unsigned long long* s_kidx = (unsigned long long*)(ws + alloc((size_t)E * 8));
    float* s_w   = (float*)(ws + alloc((size_t)E * 8 * 4));
    float* h_a   = (float*)(ws + alloc((size_t)N * 64 * 4));
    float* h_b   = (float*)(ws + alloc((size_t)N * 64 * 4));
    unsigned short* wb1 = (unsigned short*)(ws + alloc((size_t)4 * 56 * 64 * 8 * 2));
    unsigned short* wb2 = (unsigned short*)(ws + alloc((size_t)4 * 56 * 64 * 8 * 2));

    hipMemsetAsync(count, 0, (size_t)N * 4, stream);
    count_kernel<<<(E + 255) / 256, 256, 0, stream>>>(ei, count, E);
    scan_kernel<<<1, 1024, 0, stream>>>(count, row_ptr, cursor, N);
    basis_sort_kernel<<<(E + 255) / 256, 256, 0, stream>>>(ei, attr, count, cursor,
                                                           s_meta, s_kidx, s_w, E);
    build_wb<<<(4 * 56 * 64 + 255) / 256, 256, 0, stream>>>(W1, R1, wb1);
    build_wb<<<(4 * 56 * 64 + 255) / 256, 256, 0, stream>>>(W2, R2, wb2);

    layer0_kernel<<<(N + 31) / 32, 256, 0, stream>>>(x, W0, R0, B0, row_ptr,
                                                     s_meta, s_kidx, s_w, h_a, N);
    layer64_kernel<<<(N + 7) / 8, 256, 0, stream>>>(h_a, wb1, B1, row_ptr,
                                                    s_meta, s_kidx, s_w, h_b, N);
    layer64_kernel<<<(N + 7) / 8, 256, 0, stream>>>(h_b, wb2, B2, row_ptr,
                                                    s_meta, s_kidx, s_w, (float*)d_out, N);
}

// Round 4
// 1252.739 us; speedup vs baseline: 3.7915x; 3.7915x over previous
//
#include <hip/hip_runtime.h>
#include <cstdint>

// SplineConv MeshEncoder: 3 layers, K=3 DIM=3 M=27, dims 3->64->64->64.
// R4 = R1-proven structure (preproc, MFMA Phase B, layer0 register Phase B)
// with Phase A changed from LDS atomics (R2: CAS storms) to EXCLUSIVE
// OWNERSHIP: each wave owns its nodes' acc rows; lane=channel => every LDS
// cell has one writer => plain ds_read/fma/ds_write RMW, no atomics.

typedef __attribute__((ext_vector_type(8))) short short8;
typedef __attribute__((ext_vector_type(4))) float floatx4;

__device__ inline short f2bf(float f) {
    union { float f; unsigned u; } x; x.f = f;
    unsigned r = x.u + 0x7FFF + ((x.u >> 16) & 1);   // round-to-nearest-even
    return (short)(r >> 16);
}

// ---------------- preprocessing (R1/R2-proven) ----------------

__global__ void count_kernel(const int* __restrict__ ei, int* __restrict__ count, int E) {
    int e = blockIdx.x * blockDim.x + threadIdx.x;
    if (e < E) atomicAdd(&count[ei[E + e]], 1);
}

__global__ __launch_bounds__(1024) void scan_kernel(const int* __restrict__ count,
                                                    int* __restrict__ row_ptr,
                                                    int* __restrict__ cursor, int N) {
    __shared__ int wsum[16];
    __shared__ int carry_s;
    int tid = threadIdx.x, lane = tid & 63, wid = tid >> 6;
    if (tid == 0) carry_s = 0;
    __syncthreads();
    for (int base = 0; base < N; base += 1024) {
        int i = base + tid;
        int v = (i < N) ? count[i] : 0;
        int incl = v;
#pragma unroll
        for (int off = 1; off < 64; off <<= 1) {
            int t = __shfl_up(incl, off, 64);
            if (lane >= off) incl += t;
        }
        if (lane == 63) wsum[wid] = incl;
        __syncthreads();
        if (tid < 16) {
            int w = wsum[tid];
#pragma unroll
            for (int off = 1; off < 16; off <<= 1) {
                int t = __shfl_up(w, off, 16);
                if ((tid & 15) >= off) w += t;
            }
            wsum[tid] = w;
        }
        __syncthreads();
        int waveoff = (wid > 0) ? wsum[wid - 1] : 0;
        int carry = carry_s;
        int excl = carry + waveoff + incl - v;
        if (i < N) { row_ptr[i] = excl; cursor[i] = excl; }
        __syncthreads();
        if (tid == 1023) carry_s = carry + waveoff + incl;
        __syncthreads();
    }
    if (threadIdx.x == 0) row_ptr[N] = carry_s;
}

// Per edge: packed per-corner kernel indices + weights pre-scaled by 1/deg,
// scattered to dst-sorted position. s_meta = src only (ownership model).
__global__ void basis_sort_kernel(const int* __restrict__ ei, const float* __restrict__ attr,
                                  const int* __restrict__ count, int* __restrict__ cursor,
                                  int* __restrict__ s_meta,
                                  unsigned long long* __restrict__ s_kidx,
                                  float* __restrict__ s_w, int E) {
    int e = blockIdx.x * blockDim.x + threadIdx.x;
    if (e >= E) return;
    int src = ei[e];
    int dst = ei[E + e];
    float f[3]; int i0[3];
#pragma unroll
    for (int d = 0; d < 3; d++) {
        float pos = attr[e * 3 + d] * 2.0f;          // K-1 = 2
        float fl = floorf(pos);
        fl = fminf(fmaxf(fl, 0.0f), 1.0f);           // clip to [0, K-2]
        i0[d] = (int)fl;
        f[d] = pos - fl;
    }
    float invd = 1.0f / fmaxf((float)count[dst], 1.0f);
    int p = atomicAdd(&cursor[dst], 1);
    s_meta[p] = src;
    unsigned long long packed = 0;
#pragma unroll
    for (int c = 0; c < 8; c++) {
        float w = 1.0f;
        int kidx = 0;
        const int strides[3] = {1, 3, 9};
#pragma unroll
        for (int d = 0; d < 3; d++) {
            int off = (c >> d) & 1;
            w *= off ? f[d] : (1.0f - f[d]);
            kidx += (i0[d] + off) * strides[d];
        }
        packed |= ((unsigned long long)(kidx & 0xFF)) << (8 * c);
        s_w[(size_t)p * 8 + c] = w * invd;
    }
    s_kidx[p] = packed;
}

// Pre-swizzle [W(1728,64); Wr(64,64)] into bf16 MFMA B-frag order (R1-proven):
// wb[((t*56+c)*64+l)*8+j] = bf16( Wcat[c*32+(l>>4)*8+j][t*16+(l&15)] )
__global__ void build_wb(const float* __restrict__ W, const float* __restrict__ Wr,
                         unsigned short* __restrict__ wb) {
    int idx = blockIdx.x * blockDim.x + threadIdx.x;   // [0, 4*56*64)
    if (idx >= 4 * 56 * 64) return;
    int l = idx & 63;
    int c = (idx >> 6) % 56;
    int t = idx / (56 * 64);
    int q = l >> 4, o = t * 16 + (l & 15);
    short8 out;
#pragma unroll
    for (int j = 0; j < 8; j++) {
        int k = c * 32 + q * 8 + j;
        float v = (k < 1728) ? W[(size_t)k * 64 + o] : Wr[(size_t)(k - 1728) * 64 + o];
        out[j] = f2bf(v);
    }
    *(short8*)(wb + (size_t)idx * 8) = out;
}

// ---------------- layer 0 (CIN=3), R1-proven Phase B ----------------
__global__ __launch_bounds__(256) void layer0_kernel(
    const float* __restrict__ x, const float* __restrict__ W0,
    const float* __restrict__ Wr, const float* __restrict__ bias,
    const int* __restrict__ row_ptr, const int* __restrict__ s_meta,
    const unsigned long long* __restrict__ s_kidx, const float* __restrict__ s_w,
    float* __restrict__ h_out, int N) {
    constexpr int NPB = 32, KT = 84;                  // 27*3 spline + 3 root
    __shared__ __align__(16) float acc[NPB * KT];     // 10.75 KB
    int tid = threadIdx.x, lane = tid & 63, wv = tid >> 6;
    int n0 = blockIdx.x * NPB;
    for (int k = tid; k < NPB * KT; k += 256) acc[k] = 0.0f;
    __syncthreads();

    // Phase A: wave wv owns nodes n0+wv*8 .. +7. lane -> (corner c, chan i);
    // 24 distinct LDS cells per edge, single writer each -> plain RMW.
    int c = lane / 3, i = lane - c * 3;
    bool act = (lane < 24);
    for (int g2 = 0; g2 < 8; g2++) {
        int g = wv * 8 + g2;
        int n = n0 + g;
        if (n >= N) continue;
        if (lane < 3) acc[g * KT + 81 + lane] = x[(size_t)n * 3 + lane];  // root
        int rs = row_ptr[n], re = row_ptr[n + 1];
        for (int e = rs; e < re; e++) {
            int src = s_meta[e];
            unsigned long long kp = s_kidx[e];
            if (act) {
                float w = s_w[(size_t)e * 8 + c];
                float xj = x[(size_t)src * 3 + i];
                int kidx = (int)((kp >> (8 * c)) & 0xFF);
                acc[g * KT + kidx * 3 + i] += w * xj;
            }
        }
    }
    __syncthreads();

    // Phase B: o = lane, W held in 84 registers, 8 nodes per wave.
    int o = lane;
    float wreg[KT];
#pragma unroll
    for (int k = 0; k < KT; k++)
        wreg[k] = (k < 81) ? W0[k * 64 + o] : Wr[(k - 81) * 64 + o];
    float bv = bias[o];
    for (int g = wv; g < NPB; g += 4) {
        int n = n0 + g;
        if (n >= N) break;
        float s = bv;
#pragma unroll
        for (int k4 = 0; k4 < KT; k4 += 4) {
            floatx4 a = *(const floatx4*)&acc[g * KT + k4];
            s += a.x * wreg[k4] + a.y * wreg[k4 + 1] + a.z * wreg[k4 + 2] + a.w * wreg[k4 + 3];
        }
        h_out[(size_t)n * 64 + o] = fmaxf(s, 0.0f);
    }
}

// ---------------- 64-ch layers (MFMA), R1-proven Phase B ----------------
__global__ __launch_bounds__(256) void layer64_kernel(
    const float* __restrict__ h_in, const unsigned short* __restrict__ wb,
    const float* __restrict__ bias, const int* __restrict__ row_ptr,
    const int* __restrict__ s_meta, const unsigned long long* __restrict__ s_kidx,
    const float* __restrict__ s_w, float* __restrict__ h_out, int N) {
    constexpr int NPB = 8;
    constexpr int KPAD = 1796;           // row stride pad (R1-proven)
    __shared__ __align__(16) float acc[NPB * KPAD];   // 57,472 B -> 2 blocks/CU
    int tid = threadIdx.x, lane = tid & 63, wv = tid >> 6;
    int n0 = blockIdx.x * NPB;

    for (int k = tid; k < NPB * KPAD; k += 256) acc[k] = 0.0f;
    __syncthreads();

    // Phase A: wave wv exclusively owns nodes n0+wv*2+{0,1}; lane = channel.
    // Each LDS cell (slot, lane) has exactly one writer wave -> plain RMW.
    for (int g2 = 0; g2 < 2; g2++) {
        int g = wv * 2 + g2;
        int n = n0 + g;
        if (n >= N) continue;
        float* arow = &acc[g * KPAD + lane];
        arow[1728] = h_in[(size_t)n * 64 + lane];    // root slot
        int rs = row_ptr[n], re = row_ptr[n + 1];
        for (int e = rs; e < re; e++) {
            int src = s_meta[e];                      // wave-uniform -> s_load
            unsigned long long kp = s_kidx[e];
            const floatx4* wp = (const floatx4*)(s_w + (size_t)e * 8);
            floatx4 w0 = wp[0], w1 = wp[1];
            float xj = h_in[(size_t)src * 64 + lane]; // coalesced 256B/wave
            float wc[8] = {w0.x, w0.y, w0.z, w0.w, w1.x, w1.y, w1.z, w1.w};
#pragma unroll
            for (int cc = 0; cc < 8; cc++) {
                int kidx = (int)((kp >> (8 * cc)) & 0xFF);
                arow[kidx * 64] += wc[cc] * xj;       // ds_read+fma+ds_write
            }
        }
    }
    __syncthreads();

    // Phase B: wave t computes out-tile t (16 channels) for the 8 nodes.
    // A rows m>=8 duplicate rows 0..7 (discarded at store). R1-proven.
    int t = wv;
    int mq = lane >> 4;
    const float* arow = &acc[(lane & 7) * KPAD];
    floatx4 facc = {0.0f, 0.0f, 0.0f, 0.0f};
    const unsigned short* wbp = wb + ((size_t)(t * 56) * 64 + lane) * 8;
#pragma unroll 2
    for (int c = 0; c < 56; c++) {
        int ka = c * 32 + mq * 8;
        floatx4 a0 = *(const floatx4*)(arow + ka);
        floatx4 a1 = *(const floatx4*)(arow + ka + 4);
        short8 af;
        af[0] = f2bf(a0.x); af[1] = f2bf(a0.y); af[2] = f2bf(a0.z); af[3] = f2bf(a0.w);
        af[4] = f2bf(a1.x); af[5] = f2bf(a1.y); af[6] = f2bf(a1.z); af[7] = f2bf(a1.w);
        short8 bfr = *(const short8*)(wbp + (size_t)c * 64 * 8);
        facc = __builtin_amdgcn_mfma_f32_16x16x32_bf16(af, bfr, facc, 0, 0, 0);
    }

    int o = t * 16 + (lane & 15);
    float bv = bias[o];
#pragma unroll
    for (int r = 0; r < 4; r++) {
        int m = (lane >> 4) * 4 + r;
        if (m < 8) {
            int n = n0 + m;
            if (n < N) h_out[(size_t)n * 64 + o] = fmaxf(facc[r] + bv, 0.0f);
        }
    }
}

extern "C" void kernel_launch(void* const* d_in, const int* in_sizes, int n_in,
                              void* d_out, int out_size, void* d_ws, size_t ws_size,
                              hipStream_t stream) {
    (void)n_in; (void)out_size; (void)ws_size;
    const float* x    = (const float*)d_in[0];
    const int*   ei   = (const int*)d_in[1];
    const float* attr = (const float*)d_in[2];
    const float* W0 = (const float*)d_in[3];
    const float* R0 = (const float*)d_in[4];
    const float* B0 = (const float*)d_in[5];
    const float* W1 = (const float*)d_in[6];
    const float* R1 = (const float*)d_in[7];
    const float* B1 = (const float*)d_in[8];
    const float* W2 = (const float*)d_in[9];
    const float* R2 = (const float*)d_in[10];
    const float* B2 = (const float*)d_in[11];
    const int N = in_sizes[0] / 3;
    const int E = in_sizes[1] / 2;

    char* ws = (char*)d_ws;
    size_t off = 0;
    auto alloc = [&](size_t bytes) {
        size_t cur = off;
        off = (off + bytes + 255) & ~(size_t)255;
        return cur;
    };
    int* row_ptr = (int*)(ws + alloc((size_t)(N + 1) * 4));
    int* count   = (int*)(ws + alloc((size_t)N * 4));
    int* cursor  = (int*)(ws + alloc((size_t)N * 4));
    int* s_meta  = (int*)(ws + alloc((size_t)E * 4));
    unsigned long long* s_kidx = (unsigned long long*)(ws + alloc((size_t)E * 8));
    float* s_w   = (float*)(ws + alloc((size_t)E * 8 * 4));
    float* h_a   = (float*)(ws + alloc((size_t)N * 64 * 4));
    float* h_b   = (float*)(ws + alloc((size_t)N * 64 * 4));
    unsigned short* wb1 = (unsigned short*)(ws + alloc((size_t)4 * 56 * 64 * 8 * 2));
    unsigned short* wb2 = (unsigned short*)(ws + alloc((size_t)4 * 56 * 64 * 8 * 2));

    hipMemsetAsync(count, 0, (size_t)N * 4, stream);
    count_kernel<<<(E + 255) / 256, 256, 0, stream>>>(ei, count, E);
    scan_kernel<<<1, 1024, 0, stream>>>(count, row_ptr, cursor, N);
    basis_sort_kernel<<<(E + 255) / 256, 256, 0, stream>>>(ei, attr, count, cursor,
                                                           s_meta, s_kidx, s_w, E);
    build_wb<<<(4 * 56 * 64 + 255) / 256, 256, 0, stream>>>(W1, R1, wb1);
    build_wb<<<(4 * 56 * 64 + 255) / 256, 256, 0, stream>>>(W2, R2, wb2);

    layer0_kernel<<<(N + 31) / 32, 256, 0, stream>>>(x, W0, R0, B0, row_ptr,
                                                     s_meta, s_kidx, s_w, h_a, N);
    layer64_kernel<<<(N + 7) / 8, 256, 0, stream>>>(h_a, wb1, B1, row_ptr,
                                                    s_meta, s_kidx, s_w, h_b, N);
    layer64_kernel<<<(N + 7) / 8, 256, 0, stream>>>(h_b, wb2, B2, row_ptr,
                                                    s_meta, s_kidx, s_w, (float*)d_out, N);
}

// Round 5
// 950.041 us; speedup vs baseline: 4.9996x; 1.3186x over previous
//
#include <hip/hip_runtime.h>
#include <cstdint>

// SplineConv MeshEncoder: 3 layers, K=3 DIM=3 M=27, dims 3->64->64->64.
// R5 = R4-proven skeleton; layer64 Phase A rewritten as REGISTER accumulator
// (wave-uniform base -> readfirstlane + 8-case switch -> compile-time reg
// indices) with 8-edge gather batches to hide latency. Acc dumped to LDS as
// bf16 once (same values R4 converted pre-MFMA -> numerically identical),
// halving LDS to 28.9 KB -> 5 blocks/CU. Phase B reads short8 directly.

typedef __attribute__((ext_vector_type(8))) short short8;
typedef __attribute__((ext_vector_type(4))) float floatx4;

__device__ inline short f2bf(float f) {
    union { float f; unsigned u; } x; x.f = f;
    unsigned r = x.u + 0x7FFF + ((x.u >> 16) & 1);   // round-to-nearest-even
    return (short)(r >> 16);
}

// ---------------- preprocessing (R4-proven; meta now packs base<<24) -------

__global__ void count_kernel(const int* __restrict__ ei, int* __restrict__ count, int E) {
    int e = blockIdx.x * blockDim.x + threadIdx.x;
    if (e < E) atomicAdd(&count[ei[E + e]], 1);
}

__global__ __launch_bounds__(1024) void scan_kernel(const int* __restrict__ count,
                                                    int* __restrict__ row_ptr,
                                                    int* __restrict__ cursor, int N) {
    __shared__ int wsum[16];
    __shared__ int carry_s;
    int tid = threadIdx.x, lane = tid & 63, wid = tid >> 6;
    if (tid == 0) carry_s = 0;
    __syncthreads();
    for (int base = 0; base < N; base += 1024) {
        int i = base + tid;
        int v = (i < N) ? count[i] : 0;
        int incl = v;
#pragma unroll
        for (int off = 1; off < 64; off <<= 1) {
            int t = __shfl_up(incl, off, 64);
            if (lane >= off) incl += t;
        }
        if (lane == 63) wsum[wid] = incl;
        __syncthreads();
        if (tid < 16) {
            int w = wsum[tid];
#pragma unroll
            for (int off = 1; off < 16; off <<= 1) {
                int t = __shfl_up(w, off, 16);
                if ((tid & 15) >= off) w += t;
            }
            wsum[tid] = w;
        }
        __syncthreads();
        int waveoff = (wid > 0) ? wsum[wid - 1] : 0;
        int carry = carry_s;
        int excl = carry + waveoff + incl - v;
        if (i < N) { row_ptr[i] = excl; cursor[i] = excl; }
        __syncthreads();
        if (tid == 1023) carry_s = carry + waveoff + incl;
        __syncthreads();
    }
    if (threadIdx.x == 0) row_ptr[N] = carry_s;
}

// Per edge: meta = src | base<<24 (base = wave-uniform corner anchor),
// packed per-corner kidx (for layer0), weights pre-scaled by 1/deg.
__global__ void basis_sort_kernel(const int* __restrict__ ei, const float* __restrict__ attr,
                                  const int* __restrict__ count, int* __restrict__ cursor,
                                  int* __restrict__ s_meta,
                                  unsigned long long* __restrict__ s_kidx,
                                  float* __restrict__ s_w, int E) {
    int e = blockIdx.x * blockDim.x + threadIdx.x;
    if (e >= E) return;
    int src = ei[e];
    int dst = ei[E + e];
    float f[3]; int i0[3];
#pragma unroll
    for (int d = 0; d < 3; d++) {
        float pos = attr[e * 3 + d] * 2.0f;          // K-1 = 2
        float fl = floorf(pos);
        fl = fminf(fmaxf(fl, 0.0f), 1.0f);           // clip to [0, K-2]
        i0[d] = (int)fl;
        f[d] = pos - fl;
    }
    int base = i0[0] + 3 * i0[1] + 9 * i0[2];        // in {0,1,3,4,9,10,12,13}
    float invd = 1.0f / fmaxf((float)count[dst], 1.0f);
    int p = atomicAdd(&cursor[dst], 1);
    s_meta[p] = src | (base << 24);
    unsigned long long packed = 0;
#pragma unroll
    for (int c = 0; c < 8; c++) {
        float w = 1.0f;
        int kidx = 0;
        const int strides[3] = {1, 3, 9};
#pragma unroll
        for (int d = 0; d < 3; d++) {
            int off = (c >> d) & 1;
            w *= off ? f[d] : (1.0f - f[d]);
            kidx += (i0[d] + off) * strides[d];
        }
        packed |= ((unsigned long long)(kidx & 0xFF)) << (8 * c);
        s_w[(size_t)p * 8 + c] = w * invd;
    }
    s_kidx[p] = packed;
}

// Pre-swizzle [W(1728,64); Wr(64,64)] into bf16 MFMA B-frag order (R1-proven).
__global__ void build_wb(const float* __restrict__ W, const float* __restrict__ Wr,
                         unsigned short* __restrict__ wb) {
    int idx = blockIdx.x * blockDim.x + threadIdx.x;   // [0, 4*56*64)
    if (idx >= 4 * 56 * 64) return;
    int l = idx & 63;
    int c = (idx >> 6) % 56;
    int t = idx / (56 * 64);
    int q = l >> 4, o = t * 16 + (l & 15);
    short8 out;
#pragma unroll
    for (int j = 0; j < 8; j++) {
        int k = c * 32 + q * 8 + j;
        float v = (k < 1728) ? W[(size_t)k * 64 + o] : Wr[(size_t)(k - 1728) * 64 + o];
        out[j] = f2bf(v);
    }
    *(short8*)(wb + (size_t)idx * 8) = out;
}

// ---------------- layer 0 (CIN=3), R4-proven (src now masked) ----------------
__global__ __launch_bounds__(256) void layer0_kernel(
    const float* __restrict__ x, const float* __restrict__ W0,
    const float* __restrict__ Wr, const float* __restrict__ bias,
    const int* __restrict__ row_ptr, const int* __restrict__ s_meta,
    const unsigned long long* __restrict__ s_kidx, const float* __restrict__ s_w,
    float* __restrict__ h_out, int N) {
    constexpr int NPB = 32, KT = 84;
    __shared__ __align__(16) float acc[NPB * KT];
    int tid = threadIdx.x, lane = tid & 63, wv = tid >> 6;
    int n0 = blockIdx.x * NPB;
    for (int k = tid; k < NPB * KT; k += 256) acc[k] = 0.0f;
    __syncthreads();

    int c = lane / 3, i = lane - c * 3;
    bool act = (lane < 24);
    for (int g2 = 0; g2 < 8; g2++) {
        int g = wv * 8 + g2;
        int n = n0 + g;
        if (n >= N) continue;
        if (lane < 3) acc[g * KT + 81 + lane] = x[(size_t)n * 3 + lane];
        int rs = row_ptr[n], re = row_ptr[n + 1];
        for (int e = rs; e < re; e++) {
            int src = s_meta[e] & 0xFFFFFF;
            unsigned long long kp = s_kidx[e];
            if (act) {
                float w = s_w[(size_t)e * 8 + c];
                float xj = x[(size_t)src * 3 + i];
                int kidx = (int)((kp >> (8 * c)) & 0xFF);
                acc[g * KT + kidx * 3 + i] += w * xj;
            }
        }
    }
    __syncthreads();

    int o = lane;
    float wreg[KT];
#pragma unroll
    for (int k = 0; k < KT; k++)
        wreg[k] = (k < 81) ? W0[k * 64 + o] : Wr[(k - 81) * 64 + o];
    float bv = bias[o];
    for (int g = wv; g < NPB; g += 4) {
        int n = n0 + g;
        if (n >= N) break;
        float s = bv;
#pragma unroll
        for (int k4 = 0; k4 < KT; k4 += 4) {
            floatx4 a = *(const floatx4*)&acc[g * KT + k4];
            s += a.x * wreg[k4] + a.y * wreg[k4 + 1] + a.z * wreg[k4 + 2] + a.w * wreg[k4 + 3];
        }
        h_out[(size_t)n * 64 + o] = fmaxf(s, 0.0f);
    }
}

// ---------------- 64-ch layers: register Phase A + MFMA Phase B ----------------
__global__ __launch_bounds__(256) void layer64_kernel(
    const float* __restrict__ h_in, const unsigned short* __restrict__ wb,
    const float* __restrict__ bias, const int* __restrict__ row_ptr,
    const int* __restrict__ s_meta, const float* __restrict__ s_w,
    float* __restrict__ h_out, int N) {
    constexpr int NPB = 8;
    constexpr int STR = 1808;            // shorts; dword-stride 904 = even bank spread
    __shared__ __align__(16) unsigned short accb[NPB * STR];   // 28,928 B
    int tid = threadIdx.x, lane = tid & 63, wv = tid >> 6;
    int n0 = blockIdx.x * NPB;

#define CASE8(B) case B: \
    acc[B + 0] += wc0.x * xj; acc[B + 1] += wc0.y * xj; \
    acc[B + 3] += wc0.z * xj; acc[B + 4] += wc0.w * xj; \
    acc[B + 9] += wc1.x * xj; acc[B + 10] += wc1.y * xj; \
    acc[B + 12] += wc1.z * xj; acc[B + 13] += wc1.w * xj; break;

    // Phase A: wave owns rows wv*2, wv*2+1. lane = channel.
    for (int g2 = 0; g2 < 2; g2++) {
        int r = wv * 2 + g2;
        int n = n0 + r;
        unsigned short* arowb = &accb[r * STR];
        if (n >= N) {   // tail hygiene: zero the row so MFMA sees no stale LDS
            for (int k = lane; k < 1792; k += 64) arowb[k] = 0;
            continue;
        }
        float acc[27];
#pragma unroll
        for (int m = 0; m < 27; m++) acc[m] = 0.0f;
        int rs = row_ptr[n], re = row_ptr[n + 1];
        for (int eb = rs; eb < re; eb += 8) {
            int cnt = re - eb;                       // wave-uniform
            int metas[8]; float xjs[8];
#pragma unroll
            for (int j = 0; j < 8; j++) {            // 8 independent meta loads
                int e = (j < cnt) ? eb + j : re - 1;
                metas[j] = s_meta[e];
            }
#pragma unroll
            for (int j = 0; j < 8; j++)              // 8 independent gathers in flight
                xjs[j] = h_in[(size_t)(metas[j] & 0xFFFFFF) * 64 + lane];
#pragma unroll
            for (int j = 0; j < 8; j++) {
                int e = (j < cnt) ? eb + j : re - 1;
                const floatx4* wp = (const floatx4*)(s_w + (size_t)e * 8);
                floatx4 wc0 = wp[0], wc1 = wp[1];
                float xj = (j < cnt) ? xjs[j] : 0.0f;
                int base = (__builtin_amdgcn_readfirstlane(metas[j]) >> 24) & 0xF;
                switch (base) {
                    CASE8(0) CASE8(1) CASE8(3) CASE8(4)
                    CASE8(9) CASE8(10) CASE8(12) CASE8(13)
                }
            }
        }
        // dump row to LDS (bf16): slot m*64+lane, root at 1728+lane
#pragma unroll
        for (int m = 0; m < 27; m++)
            arowb[m * 64 + lane] = (unsigned short)f2bf(acc[m]);
        arowb[1728 + lane] = (unsigned short)f2bf(h_in[(size_t)n * 64 + lane]);
    }
#undef CASE8
    __syncthreads();

    // Phase B (R4-proven MFMA): wave t -> out-tile t (16 channels), 8 nodes.
    // A rows m>=8 duplicate rows 0..7 (discarded at store).
    int t = wv;
    const unsigned short* ap = accb + (lane & 7) * STR + ((lane >> 4) * 8);
    floatx4 facc = {0.0f, 0.0f, 0.0f, 0.0f};
    const unsigned short* wbp = wb + ((size_t)(t * 56) * 64 + lane) * 8;
#pragma unroll 4
    for (int c = 0; c < 56; c++) {
        short8 af = *(const short8*)(ap + c * 32);
        short8 bfr = *(const short8*)(wbp + (size_t)c * 64 * 8);
        facc = __builtin_amdgcn_mfma_f32_16x16x32_bf16(af, bfr, facc, 0, 0, 0);
    }

    int o = t * 16 + (lane & 15);
    float bv = bias[o];
#pragma unroll
    for (int r = 0; r < 4; r++) {
        int m = (lane >> 4) * 4 + r;
        if (m < 8) {
            int n = n0 + m;
            if (n < N) h_out[(size_t)n * 64 + o] = fmaxf(facc[r] + bv, 0.0f);
        }
    }
}

extern "C" void kernel_launch(void* const* d_in, const int* in_sizes, int n_in,
                              void* d_out, int out_size, void* d_ws, size_t ws_size,
                              hipStream_t stream) {
    (void)n_in; (void)out_size; (void)ws_size;
    const float* x    = (const float*)d_in[0];
    const int*   ei   = (const int*)d_in[1];
    const float* attr = (const float*)d_in[2];
    const float* W0 = (const float*)d_in[3];
    const float* R0 = (const float*)d_in[4];
    const float* B0 = (const float*)d_in[5];
    const float* W1 = (const float*)d_in[6];
    const float* R1 = (const float*)d_in[7];
    const float* B1 = (const float*)d_in[8];
    const float* W2 = (const float*)d_in[9];
    const float* R2 = (const float*)d_in[10];
    const float* B2 = (const float*)d_in[11];
    const int N = in_sizes[0] / 3;
    const int E = in_sizes[1] / 2;

    char* ws = (char*)d_ws;
    size_t off = 0;
    auto alloc = [&](size_t bytes) {
        size_t cur = off;
        off = (off + bytes + 255) & ~(size_t)255;
        return cur;
    };
    int* row_ptr = (int*)(ws + alloc((size_t)(N + 1) * 4));
    int* count   = (int*)(ws + alloc((size_t)N * 4));
    int* cursor  = (int*)(ws + alloc((size_t)N * 4));
    int* s_meta  = (int*)(ws + alloc((size_t)E * 4));
    unsigned long long* s_kidx = (unsigned long long*)(ws + alloc((size_t)E * 8));
    float* s_w   = (float*)(ws + alloc((size_t)E * 8 * 4));
    float* h_a   = (float*)(ws + alloc((size_t)N * 64 * 4));
    float* h_b   = (float*)(ws + alloc((size_t)N * 64 * 4));
    unsigned short* wb1 = (unsigned short*)(ws + alloc((size_t)4 * 56 * 64 * 8 * 2));
    unsigned short* wb2 = (unsigned short*)(ws + alloc((size_t)4 * 56 * 64 * 8 * 2));

    hipMemsetAsync(count, 0, (size_t)N * 4, stream);
    count_kernel<<<(E + 255) / 256, 256, 0, stream>>>(ei, count, E);
    scan_kernel<<<1, 1024, 0, stream>>>(count, row_ptr, cursor, N);
    basis_sort_kernel<<<(E + 255) / 256, 256, 0, stream>>>(ei, attr, count, cursor,
                                                           s_meta, s_kidx, s_w, E);
    build_wb<<<(4 * 56 * 64 + 255) / 256, 256, 0, stream>>>(W1, R1, wb1);
    build_wb<<<(4 * 56 * 64 + 255) / 256, 256, 0, stream>>>(W2, R2, wb2);

    layer0_kernel<<<(N + 31) / 32, 256, 0, stream>>>(x, W0, R0, B0, row_ptr,
                                                     s_meta, s_kidx, s_w, h_a, N);
    layer64_kernel<<<(N + 7) / 8, 256, 0, stream>>>(h_a, wb1, B1, row_ptr,
                                                    s_meta, s_w, h_b, N);
    layer64_kernel<<<(N + 7) / 8, 256, 0, stream>>>(h_b, wb2, B2, row_ptr,
                                                    s_meta, s_w, (float*)d_out, N);
}

// Round 6
// 785.984 us; speedup vs baseline: 6.0431x; 1.2087x over previous
//
#include <hip/hip_runtime.h>
#include <cstdint>

// SplineConv MeshEncoder: 3 layers, K=3 DIM=3 M=27, dims 3->64->64->64.
// R6 = R5-proven skeleton with:
//  (1) layer64 Phase A SCALARIZED: readfirstlane(wv) makes n/rs/re/e uniform
//      -> s_meta/s_w via s_load (scalar pipe), weights as SGPR FMA operands,
//      gathers saddr-form with one precomputed voffset. ~12 VALU/edge vs 37.
//  (2) parallel 3-phase scan (tile scan -> 1-wave block-sum scan -> add).

typedef __attribute__((ext_vector_type(8))) short short8;
typedef __attribute__((ext_vector_type(4))) float floatx4;

__device__ inline short f2bf(float f) {
    union { float f; unsigned u; } x; x.f = f;
    unsigned r = x.u + 0x7FFF + ((x.u >> 16) & 1);   // round-to-nearest-even
    return (short)(r >> 16);
}

// ---------------- preprocessing ----------------

__global__ void count_kernel(const int* __restrict__ ei, int* __restrict__ count, int E) {
    int e = blockIdx.x * blockDim.x + threadIdx.x;
    if (e < E) atomicAdd(&count[ei[E + e]], 1);
}

// Phase 1: per-block exclusive scan of 1024 counts -> row_ptr (local), block sum -> bsum.
__global__ __launch_bounds__(1024) void scan_tile_kernel(const int* __restrict__ count,
                                                         int* __restrict__ row_ptr,
                                                         int* __restrict__ bsum, int N) {
    __shared__ int wsum[16];
    int tid = threadIdx.x, lane = tid & 63, wid = tid >> 6;
    int i = blockIdx.x * 1024 + tid;
    int v = (i < N) ? count[i] : 0;
    int incl = v;
#pragma unroll
    for (int off = 1; off < 64; off <<= 1) {
        int t = __shfl_up(incl, off, 64);
        if (lane >= off) incl += t;
    }
    if (lane == 63) wsum[wid] = incl;
    __syncthreads();
    if (tid < 16) {
        int w = wsum[tid];
#pragma unroll
        for (int off = 1; off < 16; off <<= 1) {
            int t = __shfl_up(w, off, 16);
            if ((tid & 15) >= off) w += t;
        }
        wsum[tid] = w;
    }
    __syncthreads();
    int waveoff = (wid > 0) ? wsum[wid - 1] : 0;
    if (i < N) row_ptr[i] = waveoff + incl - v;
    if (tid == 1023) bsum[blockIdx.x] = waveoff + incl;
}

// Phase 2: one wave scans <=64 block sums -> boff (exclusive), total -> tot[0].
__global__ __launch_bounds__(64) void scan_bsum_kernel(const int* __restrict__ bsum,
                                                       int* __restrict__ boff,
                                                       int* __restrict__ tot, int nb) {
    int tid = threadIdx.x;
    int v = (tid < nb) ? bsum[tid] : 0;
    int incl = v;
#pragma unroll
    for (int off = 1; off < 64; off <<= 1) {
        int t = __shfl_up(incl, off, 64);
        if (tid >= off) incl += t;
    }
    boff[tid] = incl - v;
    if (tid == 63) tot[0] = incl;
}

// Phase 3: add block offsets; produce cursor copy and row_ptr[N].
__global__ __launch_bounds__(1024) void scan_add_kernel(int* __restrict__ row_ptr,
                                                        const int* __restrict__ boff,
                                                        const int* __restrict__ tot,
                                                        int* __restrict__ cursor, int N) {
    int i = blockIdx.x * 1024 + threadIdx.x;
    if (i < N) {
        int r = row_ptr[i] + boff[blockIdx.x];
        row_ptr[i] = r;
        cursor[i] = r;
    }
    if (i == 0) row_ptr[N] = tot[0];
}

// Per edge: meta = src | base<<24, packed per-corner kidx (layer0), weights
// pre-scaled by 1/deg, scattered to dst-sorted position. (R5-proven)
__global__ void basis_sort_kernel(const int* __restrict__ ei, const float* __restrict__ attr,
                                  const int* __restrict__ count, int* __restrict__ cursor,
                                  int* __restrict__ s_meta,
                                  unsigned long long* __restrict__ s_kidx,
                                  float* __restrict__ s_w, int E) {
    int e = blockIdx.x * blockDim.x + threadIdx.x;
    if (e >= E) return;
    int src = ei[e];
    int dst = ei[E + e];
    float f[3]; int i0[3];
#pragma unroll
    for (int d = 0; d < 3; d++) {
        float pos = attr[e * 3 + d] * 2.0f;          // K-1 = 2
        float fl = floorf(pos);
        fl = fminf(fmaxf(fl, 0.0f), 1.0f);           // clip to [0, K-2]
        i0[d] = (int)fl;
        f[d] = pos - fl;
    }
    int base = i0[0] + 3 * i0[1] + 9 * i0[2];        // in {0,1,3,4,9,10,12,13}
    float invd = 1.0f / fmaxf((float)count[dst], 1.0f);
    int p = atomicAdd(&cursor[dst], 1);
    s_meta[p] = src | (base << 24);
    unsigned long long packed = 0;
#pragma unroll
    for (int c = 0; c < 8; c++) {
        float w = 1.0f;
        int kidx = 0;
        const int strides[3] = {1, 3, 9};
#pragma unroll
        for (int d = 0; d < 3; d++) {
            int off = (c >> d) & 1;
            w *= off ? f[d] : (1.0f - f[d]);
            kidx += (i0[d] + off) * strides[d];
        }
        packed |= ((unsigned long long)(kidx & 0xFF)) << (8 * c);
        s_w[(size_t)p * 8 + c] = w * invd;
    }
    s_kidx[p] = packed;
}

// Pre-swizzle [W(1728,64); Wr(64,64)] into bf16 MFMA B-frag order (R1-proven).
__global__ void build_wb(const float* __restrict__ W, const float* __restrict__ Wr,
                         unsigned short* __restrict__ wb) {
    int idx = blockIdx.x * blockDim.x + threadIdx.x;   // [0, 4*56*64)
    if (idx >= 4 * 56 * 64) return;
    int l = idx & 63;
    int c = (idx >> 6) % 56;
    int t = idx / (56 * 64);
    int q = l >> 4, o = t * 16 + (l & 15);
    short8 out;
#pragma unroll
    for (int j = 0; j < 8; j++) {
        int k = c * 32 + q * 8 + j;
        float v = (k < 1728) ? W[(size_t)k * 64 + o] : Wr[(size_t)(k - 1728) * 64 + o];
        out[j] = f2bf(v);
    }
    *(short8*)(wb + (size_t)idx * 8) = out;
}

// ---------------- layer 0 (CIN=3), R4/R5-proven ----------------
__global__ __launch_bounds__(256) void layer0_kernel(
    const float* __restrict__ x, const float* __restrict__ W0,
    const float* __restrict__ Wr, const float* __restrict__ bias,
    const int* __restrict__ row_ptr, const int* __restrict__ s_meta,
    const unsigned long long* __restrict__ s_kidx, const float* __restrict__ s_w,
    float* __restrict__ h_out, int N) {
    constexpr int NPB = 32, KT = 84;
    __shared__ __align__(16) float acc[NPB * KT];
    int tid = threadIdx.x, lane = tid & 63, wv = tid >> 6;
    int n0 = blockIdx.x * NPB;
    for (int k = tid; k < NPB * KT; k += 256) acc[k] = 0.0f;
    __syncthreads();

    int c = lane / 3, i = lane - c * 3;
    bool act = (lane < 24);
    for (int g2 = 0; g2 < 8; g2++) {
        int g = wv * 8 + g2;
        int n = n0 + g;
        if (n >= N) continue;
        if (lane < 3) acc[g * KT + 81 + lane] = x[(size_t)n * 3 + lane];
        int rs = row_ptr[n], re = row_ptr[n + 1];
        for (int e = rs; e < re; e++) {
            int src = s_meta[e] & 0xFFFFFF;
            unsigned long long kp = s_kidx[e];
            if (act) {
                float w = s_w[(size_t)e * 8 + c];
                float xj = x[(size_t)src * 3 + i];
                int kidx = (int)((kp >> (8 * c)) & 0xFF);
                acc[g * KT + kidx * 3 + i] += w * xj;
            }
        }
    }
    __syncthreads();

    int o = lane;
    float wreg[KT];
#pragma unroll
    for (int k = 0; k < KT; k++)
        wreg[k] = (k < 81) ? W0[k * 64 + o] : Wr[(k - 81) * 64 + o];
    float bv = bias[o];
    for (int g = wv; g < NPB; g += 4) {
        int n = n0 + g;
        if (n >= N) break;
        float s = bv;
#pragma unroll
        for (int k4 = 0; k4 < KT; k4 += 4) {
            floatx4 a = *(const floatx4*)&acc[g * KT + k4];
            s += a.x * wreg[k4] + a.y * wreg[k4 + 1] + a.z * wreg[k4 + 2] + a.w * wreg[k4 + 3];
        }
        h_out[(size_t)n * 64 + o] = fmaxf(s, 0.0f);
    }
}

// ---------------- 64-ch layers: scalarized Phase A + MFMA Phase B ----------------
__global__ __launch_bounds__(256) void layer64_kernel(
    const float* __restrict__ h_in, const unsigned short* __restrict__ wb,
    const float* __restrict__ bias, const int* __restrict__ row_ptr,
    const int* __restrict__ s_meta, const float* __restrict__ s_w,
    float* __restrict__ h_out, int N) {
    constexpr int NPB = 8;
    constexpr int STR = 1808;            // shorts; dword-stride 904 = even bank spread
    __shared__ __align__(16) unsigned short accb[NPB * STR];   // 28,928 B
    int tid = threadIdx.x, lane = tid & 63;
    int wvu = __builtin_amdgcn_readfirstlane(tid >> 6);   // uniform wave id
    int n0 = blockIdx.x * NPB;

#define EDGE_FMA(EIDX, XJ) do { \
    const float* wp = s_w + (size_t)(EIDX) * 8; \
    float w0 = wp[0], w1 = wp[1], w2 = wp[2], w3 = wp[3]; \
    float w4 = wp[4], w5 = wp[5], w6 = wp[6], w7 = wp[7]; \
    float xj = (XJ); \
    switch (bases) { \
    case 0:  acc[0]+=w0*xj;  acc[1]+=w1*xj;  acc[3]+=w2*xj;  acc[4]+=w3*xj; \
             acc[9]+=w4*xj;  acc[10]+=w5*xj; acc[12]+=w6*xj; acc[13]+=w7*xj; break; \
    case 1:  acc[1]+=w0*xj;  acc[2]+=w1*xj;  acc[4]+=w2*xj;  acc[5]+=w3*xj; \
             acc[10]+=w4*xj; acc[11]+=w5*xj; acc[13]+=w6*xj; acc[14]+=w7*xj; break; \
    case 3:  acc[3]+=w0*xj;  acc[4]+=w1*xj;  acc[6]+=w2*xj;  acc[7]+=w3*xj; \
             acc[12]+=w4*xj; acc[13]+=w5*xj; acc[15]+=w6*xj; acc[16]+=w7*xj; break; \
    case 4:  acc[4]+=w0*xj;  acc[5]+=w1*xj;  acc[7]+=w2*xj;  acc[8]+=w3*xj; \
             acc[13]+=w4*xj; acc[14]+=w5*xj; acc[16]+=w6*xj; acc[17]+=w7*xj; break; \
    case 9:  acc[9]+=w0*xj;  acc[10]+=w1*xj; acc[12]+=w2*xj; acc[13]+=w3*xj; \
             acc[18]+=w4*xj; acc[19]+=w5*xj; acc[21]+=w6*xj; acc[22]+=w7*xj; break; \
    case 10: acc[10]+=w0*xj; acc[11]+=w1*xj; acc[13]+=w2*xj; acc[14]+=w3*xj; \
             acc[19]+=w4*xj; acc[20]+=w5*xj; acc[22]+=w6*xj; acc[23]+=w7*xj; break; \
    case 12: acc[12]+=w0*xj; acc[13]+=w1*xj; acc[15]+=w2*xj; acc[16]+=w3*xj; \
             acc[21]+=w4*xj; acc[22]+=w5*xj; acc[24]+=w6*xj; acc[25]+=w7*xj; break; \
    default: acc[13]+=w0*xj; acc[14]+=w1*xj; acc[16]+=w2*xj; acc[17]+=w3*xj; \
             acc[22]+=w4*xj; acc[23]+=w5*xj; acc[25]+=w6*xj; acc[26]+=w7*xj; break; } \
} while (0)

    // Phase A: wave wvu owns rows wvu*2, wvu*2+1. lane = channel. All edge
    // indices are wave-uniform -> s_load for meta/weights, SGPR FMA operands.
    for (int g2 = 0; g2 < 2; g2++) {
        int r = wvu * 2 + g2;
        int n = n0 + r;
        unsigned short* arowb = &accb[r * STR];
        if (n >= N) {   // tail hygiene: zero the row so MFMA sees no stale LDS
            for (int k = lane; k < 1792; k += 64) arowb[k] = 0;
            continue;
        }
        float acc[27];
#pragma unroll
        for (int m = 0; m < 27; m++) acc[m] = 0.0f;
        int rs = row_ptr[n], re = row_ptr[n + 1];
        int e = rs;
        // full batches of 8: scalar meta prefetch, 8 gathers in flight
        for (; e + 8 <= re; e += 8) {
            int metas[8];
#pragma unroll
            for (int j = 0; j < 8; j++) metas[j] = s_meta[e + j];    // s_load
            float xjs[8];
#pragma unroll
            for (int j = 0; j < 8; j++)                              // saddr gathers
                xjs[j] = h_in[(size_t)(metas[j] & 0xFFFFFF) * 64 + lane];
#pragma unroll
            for (int j = 0; j < 8; j++) {
                int bases = (metas[j] >> 24) & 0xF;                  // scalar
                EDGE_FMA(e + j, xjs[j]);
            }
        }
        for (; e < re; e++) {                                        // remainder
            int meta = s_meta[e];
            float xjr = h_in[(size_t)(meta & 0xFFFFFF) * 64 + lane];
            int bases = (meta >> 24) & 0xF;
            EDGE_FMA(e, xjr);
        }
        // dump row to LDS (bf16): slot m*64+lane, root at 1728+lane
#pragma unroll
        for (int m = 0; m < 27; m++)
            arowb[m * 64 + lane] = (unsigned short)f2bf(acc[m]);
        arowb[1728 + lane] = (unsigned short)f2bf(h_in[(size_t)n * 64 + lane]);
    }
#undef EDGE_FMA
    __syncthreads();

    // Phase B (R5-proven MFMA): wave t -> out-tile t (16 channels), 8 nodes.
    int t = wvu;
    const unsigned short* ap = accb + (lane & 7) * STR + ((lane >> 4) * 8);
    floatx4 facc = {0.0f, 0.0f, 0.0f, 0.0f};
    const unsigned short* wbp = wb + ((size_t)(t * 56) * 64 + lane) * 8;
#pragma unroll 4
    for (int c = 0; c < 56; c++) {
        short8 af = *(const short8*)(ap + c * 32);
        short8 bfr = *(const short8*)(wbp + (size_t)c * 64 * 8);
        facc = __builtin_amdgcn_mfma_f32_16x16x32_bf16(af, bfr, facc, 0, 0, 0);
    }

    int o = t * 16 + (lane & 15);
    float bv = bias[o];
#pragma unroll
    for (int r = 0; r < 4; r++) {
        int m = (lane >> 4) * 4 + r;
        if (m < 8) {
            int n = n0 + m;
            if (n < N) h_out[(size_t)n * 64 + o] = fmaxf(facc[r] + bv, 0.0f);
        }
    }
}

extern "C" void kernel_launch(void* const* d_in, const int* in_sizes, int n_in,
                              void* d_out, int out_size, void* d_ws, size_t ws_size,
                              hipStream_t stream) {
    (void)n_in; (void)out_size; (void)ws_size;
    const float* x    = (const float*)d_in[0];
    const int*   ei   = (const int*)d_in[1];
    const float* attr = (const float*)d_in[2];
    const float* W0 = (const float*)d_in[3];
    const float* R0 = (const float*)d_in[4];
    const float* B0 = (const float*)d_in[5];
    const float* W1 = (const float*)d_in[6];
    const float* R1 = (const float*)d_in[7];
    const float* B1 = (const float*)d_in[8];
    const float* W2 = (const float*)d_in[9];
    const float* R2 = (const float*)d_in[10];
    const float* B2 = (const float*)d_in[11];
    const int N = in_sizes[0] / 3;
    const int E = in_sizes[1] / 2;

    char* ws = (char*)d_ws;
    size_t off = 0;
    auto alloc = [&](size_t bytes) {
        size_t cur = off;
        off = (off + bytes + 255) & ~(size_t)255;
        return cur;
    };
    int* row_ptr = (int*)(ws + alloc((size_t)(N + 1) * 4));
    int* count   = (int*)(ws + alloc((size_t)N * 4));
    int* cursor  = (int*)(ws + alloc((size_t)N * 4));
    int* bsum    = (int*)(ws + alloc(64 * 4));
    int* boff    = (int*)(ws + alloc(64 * 4));
    int* tot     = (int*)(ws + alloc(4));
    int* s_meta  = (int*)(ws + alloc((size_t)E * 4));
    unsigned long long* s_kidx = (unsigned long long*)(ws + alloc((size_t)E * 8));
    float* s_w   = (float*)(ws + alloc((size_t)E * 8 * 4));
    float* h_a   = (float*)(ws + alloc((size_t)N * 64 * 4));
    float* h_b   = (float*)(ws + alloc((size_t)N * 64 * 4));
    unsigned short* wb1 = (unsigned short*)(ws + alloc((size_t)4 * 56 * 64 * 8 * 2));
    unsigned short* wb2 = (unsigned short*)(ws + alloc((size_t)4 * 56 * 64 * 8 * 2));

    int nb = (N + 1023) / 1024;   // 49 <= 64

    hipMemsetAsync(count, 0, (size_t)N * 4, stream);
    count_kernel<<<(E + 255) / 256, 256, 0, stream>>>(ei, count, E);
    scan_tile_kernel<<<nb, 1024, 0, stream>>>(count, row_ptr, bsum, N);
    scan_bsum_kernel<<<1, 64, 0, stream>>>(bsum, boff, tot, nb);
    scan_add_kernel<<<nb, 1024, 0, stream>>>(row_ptr, boff, tot, cursor, N);
    basis_sort_kernel<<<(E + 255) / 256, 256, 0, stream>>>(ei, attr, count, cursor,
                                                           s_meta, s_kidx, s_w, E);
    build_wb<<<(4 * 56 * 64 + 255) / 256, 256, 0, stream>>>(W1, R1, wb1);
    build_wb<<<(4 * 56 * 64 + 255) / 256, 256, 0, stream>>>(W2, R2, wb2);

    layer0_kernel<<<(N + 31) / 32, 256, 0, stream>>>(x, W0, R0, B0, row_ptr,
                                                     s_meta, s_kidx, s_w, h_a, N);
    layer64_kernel<<<(N + 7) / 8, 256, 0, stream>>>(h_a, wb1, B1, row_ptr,
                                                    s_meta, s_w, h_b, N);
    layer64_kernel<<<(N + 7) / 8, 256, 0, stream>>>(h_b, wb2, B2, row_ptr,
                                                    s_meta, s_w, (float*)d_out, N);
}